// Round 9
// baseline (270.280 us; speedup 1.0000x reference)
//
#include <hip/hip_runtime.h>

#define IMG 512
#define HW (IMG * IMG)
#define NB 32
#define NIMG 64
#define BAND 32
#define NBAND (IMG / BAND)          // 16 bands per image
#define NBLK (NIMG * NBAND)         // 1024 blocks
#define NSTG 5                      // stages per wave; 2 waves = 10 iterations
#define HALO (2 * NSTG)             // 10 rows per 5-stage group
#define T0OFF 20                    // wave0 starts at B - 20 (full 10-iter halo)
#define NSTEP2 18                   // quad-row iterations: t = B-20+4k, k=0..17
#define INF __builtin_inff()

// DPP whole-wave shift-by-1 (CDNA keeps Vega wave_shl/shr DPP controls).
static __device__ __forceinline__ float dpp_from_prev(float v, float ident) {
    return __int_as_float(__builtin_amdgcn_update_dpp(
        __float_as_int(ident), __float_as_int(v), 0x138, 0xF, 0xF, false));
}
static __device__ __forceinline__ float dpp_from_next(float v, float ident) {
    return __int_as_float(__builtin_amdgcn_update_dpp(
        __float_as_int(ident), __float_as_int(v), 0x130, 0xF, 0xF, false));
}

// One lane owns 8 contiguous columns: a = cols[8l..8l+3], b = cols[8l+4..8l+7].
struct Row { float4 a, b; };

static __device__ __forceinline__ float min3f(float a, float b, float c) { return fminf(fminf(a, b), c); }
static __device__ __forceinline__ float max3f(float a, float b, float c) { return fmaxf(fmaxf(a, b), c); }

static __device__ __forceinline__ Row splat(float v) {
    Row r;
    r.a = make_float4(v, v, v, v);
    r.b = make_float4(v, v, v, v);
    return r;
}

static __device__ __forceinline__ Row rmin3(const Row& x, const Row& y, const Row& z) {
    Row o;
    const float* px = (const float*)&x;
    const float* py = (const float*)&y;
    const float* pz = (const float*)&z;
    float* po = (float*)&o;
#pragma unroll
    for (int i = 0; i < 8; ++i) po[i] = min3f(px[i], py[i], pz[i]);
    return o;
}

static __device__ __forceinline__ Row rmax3(const Row& x, const Row& y, const Row& z) {
    Row o;
    const float* px = (const float*)&x;
    const float* py = (const float*)&y;
    const float* pz = (const float*)&z;
    float* po = (float*)&o;
#pragma unroll
    for (int i = 0; i < 8; ++i) po[i] = max3f(px[i], py[i], pz[i]);
    return o;
}

static __device__ __forceinline__ Row hmin3(const Row& v) {
    float shl = dpp_from_prev(v.b.w, INF);
    float shr = dpp_from_next(v.a.x, INF);
    Row o;
    o.a.x = min3f(shl,   v.a.x, v.a.y);
    o.a.y = min3f(v.a.x, v.a.y, v.a.z);
    o.a.z = min3f(v.a.y, v.a.z, v.a.w);
    o.a.w = min3f(v.a.z, v.a.w, v.b.x);
    o.b.x = min3f(v.a.w, v.b.x, v.b.y);
    o.b.y = min3f(v.b.x, v.b.y, v.b.z);
    o.b.z = min3f(v.b.y, v.b.z, v.b.w);
    o.b.w = min3f(v.b.z, v.b.w, shr);
    return o;
}

static __device__ __forceinline__ Row hmax3(const Row& v) {
    float shl = dpp_from_prev(v.b.w, -INF);
    float shr = dpp_from_next(v.a.x, -INF);
    Row o;
    o.a.x = max3f(shl,   v.a.x, v.a.y);
    o.a.y = max3f(v.a.x, v.a.y, v.a.z);
    o.a.z = max3f(v.a.y, v.a.z, v.a.w);
    o.a.w = max3f(v.a.z, v.a.w, v.b.x);
    o.b.x = max3f(v.a.w, v.b.x, v.b.y);
    o.b.y = max3f(v.b.x, v.b.y, v.b.z);
    o.b.z = max3f(v.b.y, v.b.z, v.b.w);
    o.b.w = max3f(v.b.z, v.b.w, shr);
    return o;
}

// out = relu(x - relu(mp - mn)) == med3(0, x, x-(mp-mn)) for consumed outputs.
// Verified bit-exact on-harness (absmax 0.0, rounds 2-8).
static __device__ __forceinline__ Row relu_out(const Row& x, const Row& mp, const Row& mn) {
    Row o;
    const float* px = (const float*)&x;
    const float* pp = (const float*)&mp;
    const float* pm = (const float*)&mn;
    float* po = (float*)&o;
#pragma unroll
    for (int i = 0; i < 8; ++i) {
        float d = pp[i] - pm[i];
        po[i] = __builtin_amdgcn_fmed3f(0.f, px[i], px[i] - d);
    }
    return o;
}

// Branch-free row load, index clamped; OOB values overridden at consume time.
static __device__ __forceinline__ Row load_row_clamped(const float* __restrict__ p,
                                                       int r, int lane) {
    const int rc = min(max(r, 0), IMG - 1);
    const float4* q = (const float4*)(p + (size_t)rc * IMG + lane * 8);
    Row o;
    o.a = q[0];
    o.b = q[1];
    return o;
}

// Row-paired skeletonize stage step (round-0 verified structure).
template <bool EDGE>
static __device__ __forceinline__ void step2(Row (&x)[2], Row (&mn)[2],
                                             Row& in0, Row& in1, int t) {
    Row vmin0 = rmin3(x[0], x[1], in0);
    Row vmin1 = rmin3(x[1], in0, in1);
    Row mna = hmin3(vmin0);
    Row mnb = hmin3(vmin1);
    if (EDGE) {
        if ((unsigned)(t - 1) >= IMG) mna = splat(-INF);
        if ((unsigned)t >= IMG) mnb = splat(-INF);
    }
    Row vmax0 = rmax3(mn[0], mn[1], mna);
    Row vmax1 = rmax3(mn[1], mna, mnb);
    Row mp0 = hmax3(vmax0);
    Row mp1 = hmax3(vmax1);
    Row out0 = relu_out(x[0], mp0, mn[1]);
    Row out1 = relu_out(x[1], mp1, mna);
    if (EDGE) {
        if ((unsigned)(t - 2) >= IMG) out0 = splat(INF);
        if ((unsigned)(t - 1) >= IMG) out1 = splat(INF);
    }
    x[0] = in0;  x[1] = in1;
    mn[0] = mna; mn[1] = mnb;
    in0 = out0;  in1 = out1;
}

// Two-wave producer-consumer pipeline, QUAD-ROW iterations.
// wave0 = iterations 0..4 (src -> LDS ring), wave1 = iterations 5..9
// (LDS ring -> reduction). Each loop iteration advances TWO row-pairs
// through both wave's 5-stage chains with ONE barrier (R8 post-mortem:
// halving bytes bought ~0; the levers left are per-iteration fixed costs —
// loop control, rotation, barrier — so amortize them 2x: 36 -> 18 iters).
//
// Ring hazard audit (unchanged from R8, verified): step k writes slot k&1
// pre-barrier, reads it post-barrier; the next write to that slot (k+2) is
// separated by barrier k+1 -> race-free.
//
// Dependency audit: kept outputs v in [B, B+31] need wave1 inputs u in
// [v-10, v+10]; wave0 output u is valid for u >= B-10 (t0 = B-20). Warm-up
// garbage feeds discarded outputs only and ages out of the finite
// 2-row/stage state — same induction as the verified R0/R8 kernels.
template <bool EDGE>
static __device__ __forceinline__ void pipe(const float* __restrict__ src,
                                            const float* __restrict__ wp,
                                            float4 (*ring)[4][128],
                                            int B, int lane, int wid,
                                            float& s_prod, float& s_val) {
    Row x[NSTG][2], mn[NSTG][2];
#pragma unroll
    for (int j = 0; j < NSTG; ++j) {
        x[j][0] = splat(INF);   x[j][1] = splat(INF);
        mn[j][0] = splat(-INF); mn[j][1] = splat(-INF);
    }
    const int t0 = B - T0OFF;
    Row pre0 = splat(0.f), pre1 = splat(0.f), pre2 = splat(0.f), pre3 = splat(0.f);
    if (wid == 0) {
        pre0 = load_row_clamped(src, t0, lane);
        pre1 = load_row_clamped(src, t0 + 1, lane);
        pre2 = load_row_clamped(src, t0 + 2, lane);
        pre3 = load_row_clamped(src, t0 + 3, lane);
    }
#pragma unroll 1
    for (int k = 0; k < NSTEP2; ++k) {
        const int t = t0 + 4 * k;
        if (wid == 0) {
            // prefetch next iteration's 4 rows; in flight across both chains
            Row nxt0 = load_row_clamped(src, t + 4, lane);
            Row nxt1 = load_row_clamped(src, t + 5, lane);
            Row nxt2 = load_row_clamped(src, t + 6, lane);
            Row nxt3 = load_row_clamped(src, t + 7, lane);
            // pair A: rows t, t+1
            Row in0 = pre0, in1 = pre1;
            if (EDGE) {
                if ((unsigned)t >= IMG) in0 = splat(INF);
                if ((unsigned)(t + 1) >= IMG) in1 = splat(INF);
            }
#pragma unroll
            for (int j = 0; j < NSTG; ++j)
                step2<EDGE>(x[j], mn[j], in0, in1, t - 2 * j);
            ring[k & 1][0][lane * 2] = in0.a;
            ring[k & 1][0][lane * 2 + 1] = in0.b;
            ring[k & 1][1][lane * 2] = in1.a;
            ring[k & 1][1][lane * 2 + 1] = in1.b;
            // pair B: rows t+2, t+3
            Row in2 = pre2, in3 = pre3;
            if (EDGE) {
                if ((unsigned)(t + 2) >= IMG) in2 = splat(INF);
                if ((unsigned)(t + 3) >= IMG) in3 = splat(INF);
            }
#pragma unroll
            for (int j = 0; j < NSTG; ++j)
                step2<EDGE>(x[j], mn[j], in2, in3, t + 2 - 2 * j);
            ring[k & 1][2][lane * 2] = in2.a;
            ring[k & 1][2][lane * 2 + 1] = in2.b;
            ring[k & 1][3][lane * 2] = in3.a;
            ring[k & 1][3][lane * 2 + 1] = in3.b;
            pre0 = nxt0; pre1 = nxt1; pre2 = nxt2; pre3 = nxt3;
        }
        __syncthreads();
        if (wid == 1) {
            // pair A: stage-5 input rows uA, uA+1 -> final rows vA, vA+1
            const int uA = t - HALO;
            const int vA = uA - HALO;
            const bool inbA = (unsigned)(vA - B) < BAND;
            Row w0, w1;
            if (inbA) {  // guarded weight loads (R0/R8-style), issued before
                         // the chain so 5 stages of VALU cover their latency
                const float4* q0 = (const float4*)(wp + (size_t)vA * IMG + lane * 8);
                w0.a = q0[0]; w0.b = q0[1];
                const float4* q1 = (const float4*)(wp + (size_t)(vA + 1) * IMG + lane * 8);
                w1.a = q1[0]; w1.b = q1[1];
            }
            Row in0, in1;
            in0.a = ring[k & 1][0][lane * 2];
            in0.b = ring[k & 1][0][lane * 2 + 1];
            in1.a = ring[k & 1][1][lane * 2];
            in1.b = ring[k & 1][1][lane * 2 + 1];
#pragma unroll
            for (int j = 0; j < NSTG; ++j)
                step2<EDGE>(x[j], mn[j], in0, in1, uA - 2 * j);
            if (inbA) {
                const float* p0 = (const float*)&in0;
                const float* p1 = (const float*)&in1;
                const float* q0 = (const float*)&w0;
                const float* q1 = (const float*)&w1;
#pragma unroll
                for (int i = 0; i < 8; ++i) {
                    s_prod += p0[i] * q0[i] + p1[i] * q1[i];
                    s_val += p0[i] + p1[i];
                }
            }
            // pair B: rows uA+2 -> vA+2 (weight pair loaded here so only one
            // w-pair is ever live; chain B covers its latency)
            const int vB = vA + 2;
            const bool inbB = (unsigned)(vB - B) < BAND;
            Row w2, w3;
            if (inbB) {
                const float4* q2 = (const float4*)(wp + (size_t)vB * IMG + lane * 8);
                w2.a = q2[0]; w2.b = q2[1];
                const float4* q3 = (const float4*)(wp + (size_t)(vB + 1) * IMG + lane * 8);
                w3.a = q3[0]; w3.b = q3[1];
            }
            Row in2, in3;
            in2.a = ring[k & 1][2][lane * 2];
            in2.b = ring[k & 1][2][lane * 2 + 1];
            in3.a = ring[k & 1][3][lane * 2];
            in3.b = ring[k & 1][3][lane * 2 + 1];
#pragma unroll
            for (int j = 0; j < NSTG; ++j)
                step2<EDGE>(x[j], mn[j], in2, in3, uA + 2 - 2 * j);
            if (inbB) {
                const float* p2 = (const float*)&in2;
                const float* p3 = (const float*)&in3;
                const float* q2 = (const float*)&w2;
                const float* q3 = (const float*)&w3;
#pragma unroll
                for (int i = 0; i < 8; ++i) {
                    s_prod += p2[i] * q2[i] + p3[i] * q3[i];
                    s_val += p2[i] + p3[i];
                }
            }
        }
    }
}

// __launch_bounds__(128,1): VGPR cap 256 (hipcc spills past 256/min_waves —
// rounds 2/4/5). 1024 blocks x 2 waves = 2 waves/SIMD; 4 blocks/CU x 16 KB
// LDS = 64 KB < 160 KB. Finalize is FOLDED IN via fence+counter last-block
// pattern (saves one serialized 1-thread dispatch of the ~66 us launch tail).
__global__ __launch_bounds__(128, 1) void skel10_pipe(const float* __restrict__ yp,
                                                      const float* __restrict__ yt,
                                                      double* __restrict__ acc,
                                                      unsigned* __restrict__ ctr,
                                                      float* __restrict__ out) {
    __shared__ float4 ring[2][4][128];   // [slot][row][lane*2+half] = 16 KB
    const int blk = blockIdx.x;
    const int img = blk >> 4, band = blk & (NBAND - 1);
    // skel(pred) pairs with y_true c1; skel(true) pairs with y_pred c1.
    const float* src = (img < NB) ? yp + (size_t)(2 * img + 1) * HW
                                  : yt + (size_t)(2 * (img - NB) + 1) * HW;
    const float* wp = (img < NB) ? yt + (size_t)(2 * img + 1) * HW
                                 : yp + (size_t)(2 * (img - NB) + 1) * HW;
    const int lane = threadIdx.x & 63;
    const int wid = threadIdx.x >> 6;
    const int B = band * BAND;

    float s_prod = 0.f, s_val = 0.f;
    if (band == 0 || band == NBAND - 1)
        pipe<true>(src, wp, ring, B, lane, wid, s_prod, s_val);
    else
        pipe<false>(src, wp, ring, B, lane, wid, s_prod, s_val);

    if (wid == 1) {
#pragma unroll
        for (int off = 32; off; off >>= 1) {
            s_prod += __shfl_down(s_prod, off);
            s_val += __shfl_down(s_val, off);
        }
        if (lane == 0) {
            const int base = (img < NB) ? 0 : 2;
            atomicAdd(&acc[base], (double)s_prod);
            atomicAdd(&acc[base + 1], (double)s_val);
            // release: make this block's acc adds visible before the count
            __threadfence();
            unsigned old = atomicAdd(ctr, 1u);
            if (old == NBLK - 1) {
                // acquire; read acc through RMW atomics (coherent point —
                // plain loads could hit a stale per-XCD L2 line)
                __threadfence();
                double a0 = atomicAdd(&acc[0], 0.0);
                double a1 = atomicAdd(&acc[1], 0.0);
                double a2 = atomicAdd(&acc[2], 0.0);
                double a3 = atomicAdd(&acc[3], 0.0);
                double tprec = (a0 + 1.0) / (a1 + 1.0);
                double tsens = (a2 + 1.0) / (a3 + 1.0);
                out[0] = (float)(1.0 - 2.0 * (tprec * tsens) / (tprec + tsens));
            }
        }
    }
}

extern "C" void kernel_launch(void* const* d_in, const int* in_sizes, int n_in,
                              void* d_out, int out_size, void* d_ws, size_t ws_size,
                              hipStream_t stream) {
    (void)in_sizes; (void)n_in; (void)out_size; (void)ws_size;
    const float* yp = (const float*)d_in[0];
    const float* yt = (const float*)d_in[1];
    float* out = (float*)d_out;

    // Workspace: 4 double accumulators + completion counter.
    double* acc = (double*)d_ws;
    unsigned* ctr = (unsigned*)(acc + 4);
    hipMemsetAsync(acc, 0, 4 * sizeof(double) + sizeof(unsigned), stream);

    skel10_pipe<<<NBLK, 128, 0, stream>>>(yp, yt, acc, ctr, out);
}